// Round 17
// baseline (116.819 us; speedup 1.0000x reference)
//
#include <hip/hip_runtime.h>
#include <stdint.h>

typedef __attribute__((ext_vector_type(8))) short short8;
typedef __attribute__((ext_vector_type(4))) float f32x4;
typedef __attribute__((ext_vector_type(4))) uint32_t u32x4;

#if __has_builtin(__builtin_amdgcn_exp2f)
#define EXP2(x) __builtin_amdgcn_exp2f(x)
#else
#define EXP2(x) exp2f(x)
#endif

// round-nearest-ties-away bf16: statistically unbiased, 2 VALU ops
__device__ __forceinline__ short f2bf(float f){
  uint32_t u = __builtin_bit_cast(uint32_t, f);
  return (short)((u + 0x8000u) >> 16);
}
// pack two rounded bf16 (lo in low half): 2 adds + 1 v_perm (proven through R15;
// NOTE: v_cvt_pk_bf16_f32 here FAILS accuracy — R3/R16 both showed ~2e-2 absmax)
__device__ __forceinline__ uint32_t pk2(float lo, float hi){
  uint32_t a = __builtin_bit_cast(uint32_t, lo) + 0x8000u;
  uint32_t b = __builtin_bit_cast(uint32_t, hi) + 0x8000u;
#if __has_builtin(__builtin_amdgcn_perm)
  return __builtin_amdgcn_perm(b, a, 0x07060302u);   // [b3 b2 a3 a2]
#else
  return (b & 0xFFFF0000u) | (a >> 16);
#endif
}
__device__ __forceinline__ void gload16(const void* g, void* l){
  __builtin_amdgcn_global_load_lds((const __attribute__((address_space(1))) void*)g,
                                   (__attribute__((address_space(3))) void*)l, 16, 0, 0);
}

// ---------------- fp32 -> bf16 conversion of q,k,v,Wq,Wk,Wv,Wo ----------------
__global__ __launch_bounds__(512) void cvt_all(
    const float* __restrict__ q, const float* __restrict__ k, const float* __restrict__ v,
    const float* __restrict__ wq, const float* __restrict__ wk, const float* __restrict__ wv,
    const float* __restrict__ wo, short* __restrict__ dst){
  const size_t SQ = 4096ull*1024ull, NW = 1024ull*1024ull;
  size_t e = (size_t)(blockIdx.x*512u + threadIdx.x)*8ull;
  const float* src; size_t rel;
  if (e < 3*SQ){ size_t which = e / SQ; src = which==0?q:(which==1?k:v); rel = e - which*SQ; }
  else { size_t e2 = e - 3*SQ; size_t which = e2 / NW;
         src = which==0?wq:(which==1?wk:(which==2?wv:wo)); rel = e2 - which*NW; }
  float4 a = *(const float4*)(src + rel);
  float4 b = *(const float4*)(src + rel + 4);
  u32x4 r = { pk2(a.x,a.y), pk2(a.z,a.w), pk2(b.x,b.y), pk2(b.z,b.w) };
  *(u32x4*)(dst + e) = r;
}

// ---------------- NT GEMM core: 128x128 tile, BK=64, XOR-swizzled LDS ----------------
// NWAVE=4: 2x2 wave grid, 64x64/wave, acc[4][4] (0.5 ds_reads/MFMA).
// NWAVE=8: 2x4 wave grid, 64x32/wave, acc[4][2].
// MODE 0: bf16 head-scatter [b,h,s,d]. MODE 1: f32 linear.
// MODE 2: bf16 transposed head-scatter [b,h,d,s] via operand-swapped MFMA (D = C^T natively).
template<int MODE, int NWAVE>
__device__ __forceinline__ void gemm_body(const short* __restrict__ A, const short* __restrict__ Bw,
    const float* __restrict__ bias, void* __restrict__ Cout, float scale, int m0, int n0){
  const int K = 1024;
  const int NT  = NWAVE*64;
  const int SW  = 1024/NT;          // staging sweeps per 128x64 half (16KB / (NT*16B))
  const int RPS = NT/8;             // rows per sweep (multiple of 8 -> row&7 invariant)
  const int NI  = (NWAVE==4) ? 4 : 2;
  const int WCOL = NI*16;
  __shared__ short Al[128*64];
  __shared__ short Bl[128*64];
  int tid = threadIdx.x;
  int w = tid >> 6, lane = tid & 63, lr = lane & 15, lg = lane >> 4;
  int wr = (NWAVE==4) ? (w >> 1) : (w >> 2);
  int wc = (NWAVE==4) ? (w & 1)  : (w & 3);
  f32x4 acc[4][NI] = {};
  int row0 = tid >> 3;
  int qc0  = (tid & 7) ^ (row0 & 7);
  const short* Ag = A  + (size_t)(m0 + row0)*K + qc0*8;
  const short* Bg = Bw + (size_t)(n0 + row0)*K + qc0*8;
  char* Alb = (char*)Al + tid*16;
  char* Blb = (char*)Bl + tid*16;
  int ra[4], rb[NI];
#pragma unroll
  for (int mi=0; mi<4; ++mi) ra[mi] = wr*64 + mi*16 + lr;
#pragma unroll
  for (int ni=0; ni<NI; ++ni) rb[ni] = wc*WCOL + ni*16 + lr;
  for (int k0 = 0; k0 < K; k0 += 64){
#pragma unroll
    for (int s=0; s<SW; ++s) gload16(Ag + k0 + (size_t)(s*RPS)*K, Alb + s*NT*16);
#pragma unroll
    for (int s=0; s<SW; ++s) gload16(Bg + k0 + (size_t)(s*RPS)*K, Blb + s*NT*16);
    __syncthreads();
#pragma unroll
    for (int kk=0; kk<2; ++kk){
      short8 av[4], bv[NI];
#pragma unroll
      for (int mi=0; mi<4; ++mi)
        av[mi] = *(const short8*)((char*)Al + ra[mi]*128 + (((kk*4 + lg) ^ (ra[mi] & 7)) << 4));
#pragma unroll
      for (int ni=0; ni<NI; ++ni)
        bv[ni] = *(const short8*)((char*)Bl + rb[ni]*128 + (((kk*4 + lg) ^ (rb[ni] & 7)) << 4));
#pragma unroll
      for (int mi=0; mi<4; ++mi)
#pragma unroll
        for (int ni=0; ni<NI; ++ni){
          if (MODE == 2)
            acc[mi][ni] = __builtin_amdgcn_mfma_f32_16x16x32_bf16(bv[ni], av[mi], acc[mi][ni], 0, 0, 0);
          else
            acc[mi][ni] = __builtin_amdgcn_mfma_f32_16x16x32_bf16(av[mi], bv[ni], acc[mi][ni], 0, 0, 0);
        }
    }
    __syncthreads();
  }
#pragma unroll
  for (int ni=0; ni<NI; ++ni){
#pragma unroll
    for (int mi=0; mi<4; ++mi){
      if (MODE == 2){
        // D = C^T: fragment row = d-dim, col = s-dim. 16 consecutive s per lr-group -> 32B segments.
        int srow = m0 + wr*64 + mi*16 + lr;
        int b = srow >> 11, s = srow & 2047;
#pragma unroll
        for (int i2=0; i2<4; ++i2){
          int dcol = n0 + wc*WCOL + ni*16 + lg*4 + i2;
          int h = dcol >> 6, d = dcol & 63;
          float val = acc[mi][ni][i2] + bias[dcol];
          ((short*)Cout)[(((size_t)(b*16 + h))*64 + d)*2048 + s] = f2bf(val);
        }
      } else {
        int col = n0 + wc*WCOL + ni*16 + lr;
        float bb = bias[col];
#pragma unroll
        for (int i2=0; i2<4; ++i2){
          int row = m0 + wr*64 + mi*16 + lg*4 + i2;
          float val = (acc[mi][ni][i2] + bb) * scale;
          if (MODE == 0){
            int b = row >> 11, s = row & 2047, h = col >> 6, d = col & 63;
            ((short*)Cout)[(((size_t)(b*16 + h))*2048 + s)*64 + d] = f2bf(val);
          } else {
            ((float*)Cout)[(size_t)row*1024 + col] = val;
          }
        }
      }
    }
  }
}

__global__ __launch_bounds__(256) void gemm_qkv(
    const short* __restrict__ qb, const short* __restrict__ kb, const short* __restrict__ vb,
    const short* __restrict__ Wqb, const short* __restrict__ Wkb, const short* __restrict__ Wvb,
    const float* __restrict__ bq, const float* __restrict__ bk, const float* __restrict__ bv,
    short* __restrict__ Qh, short* __restrict__ Kh, short* __restrict__ VhT, float qscale){
  int f = blockIdx.y*gridDim.x + blockIdx.x;              // 0..767
  int L = (f & 7)*96 + (f >> 3);                          // XCD-contiguous (768 % 8 == 0)
  int z = L >> 8, r = L & 255;
  int m0 = (r >> 3)*128, n0 = (r & 7)*128;
  const short* A  = z==0 ? qb  : (z==1 ? kb  : vb);
  const short* Bw = z==0 ? Wqb : (z==1 ? Wkb : Wvb);
  const float* bi = z==0 ? bq  : (z==1 ? bk  : bv);
  short* C        = z==0 ? Qh  : (z==1 ? Kh  : VhT);
  if (z == 2) gemm_body<2,4>(A, Bw, bi, (void*)C, 1.0f, m0, n0);
  else        gemm_body<0,4>(A, Bw, bi, (void*)C, z==0 ? qscale : 1.0f, m0, n0);
}

__global__ __launch_bounds__(512) void gemm_out(const short* __restrict__ A, const short* __restrict__ Bw,
    const float* __restrict__ bias, float* __restrict__ Cout){
  int f = blockIdx.y*gridDim.x + blockIdx.x;              // 0..255
  int L = (f & 7)*32 + (f >> 3);
  int m0 = (L >> 3)*128, n0 = (L & 7)*128;
  gemm_body<1,8>(A, Bw, bias, (void*)Cout, 1.0f, m0, n0);
}

// ---------------- flash attention: 8 waves x 16 q-rows, register P, pair-loop (1 barrier / 2 tiles) ----------------
// Swapped QK^T with permuted K-rows (R6-verified): iteration nf covers K rows
// R = 32*(nf>>1) + 8*(lr>>2) + 4*(nf&1) + (lr&3); lane(lg) accumulates scores for
// k = 32c + 8*lg + 4*(nf&1) + i2 — exactly the PV A-fragment set (P never leaves regs).
// V pre-transposed by gemm_qkv (VhT[b,h,d,s]) -> staged like K; PV B-frag = ds_read_b128.
// lsum via ones-MFMAs. Q pre-scaled by log2(e)/8 -> p = exp2(z).
__global__ __launch_bounds__(512) void attn_fwd(const short* __restrict__ Qh, const short* __restrict__ Kh,
    const short* __restrict__ VhT, short* __restrict__ AO){
  const int S = 2048;
  int i = blockIdx.y*gridDim.x + blockIdx.x;   // 512 wgs
  int L = (i & 7)*64 + (i >> 3);
  int bh = L >> 4, qt = L & 15;
  __shared__ short Kl[4][4096];      // 4-buffer K; read-slot swizzle, source-side
  __shared__ short Vl[4][4096];      // 4-buffer V^T[d][k-chunk ^ (d&7)]
  int tid = threadIdx.x, w = tid >> 6, lane = tid & 63, lr = lane & 15, lg = lane >> 4;
  const short* Qb = Qh  + (size_t)bh*S*64;
  const short* Kb = Kh  + (size_t)bh*S*64;
  const short* Vb = VhT + (size_t)bh*64*2048;   // 64 d-rows of length S
  int q0 = qt*128 + w*16;
  short8 aq[2];
#pragma unroll
  for (int h=0; h<2; ++h)
    aq[h] = *(const short8*)&Qb[(size_t)(q0 + lr)*64 + h*32 + lg*8];
  f32x4 o[4] = {};
  f32x4 o1 = {};                      // row-sums of P via ones-MFMA
  short8 ones;
#pragma unroll
  for (int j=0; j<8; ++j) ones[j] = (short)0x3F80;   // bf16 1.0
  // K staging: 1 gload16/thread; LDS dest linear, source pre-swizzled
  int koff = tid*16;
  int kr = tid >> 3, kc = tid & 7;
  int ksw = (kr & 3) | (((kr >> 3) & 1) << 2);
  int ksrc = kr*64 + ((kc ^ ksw) << 3);
  // V staging: 1 gload16/thread; row d = tid>>3 (stride 2048), chunk XOR by d&7
  int vsrc = kr*2048 + ((kc ^ (kr & 7)) << 3);
  // K read addressing
  int Rbase = 8*(lr >> 2) + (lr & 3);
  int sR = (lr & 3) | (((lr >> 2) & 1) << 2);
  int slot0 = (lg ^ sR) << 3, slot1 = ((lg + 4) ^ sR) << 3;
  // V read addressing: chunk xor term
  int vx = lr & 7;
  // ---- prologue: tiles 0..3 ----
#pragma unroll
  for (int t=0; t<4; ++t){
    gload16(Kb + (size_t)t*4096 + ksrc, (char*)&Kl[t][0] + koff);
    gload16(Vb + vsrc + t*64,           (char*)&Vl[t][0] + koff);
  }
  asm volatile("s_waitcnt vmcnt(4)" ::: "memory");  // tiles 0,1 landed; 2,3 in flight
  __builtin_amdgcn_sched_barrier(0);
  __builtin_amdgcn_s_barrier();

  for (int p = 0; p < 16; ++p){
    short8 pa[2][2];   // [u][c]
    // QK^T + softmax for both tiles of the pair (independent chains)
    __builtin_amdgcn_s_setprio(1);
#pragma unroll
    for (int u = 0; u < 2; ++u){
      const short* Kbuf = &Kl[(2*p + u) & 3][0];
      uint32_t Wp[2][2][2];   // [c][nf0][s]
#pragma unroll
      for (int nf=0; nf<4; ++nf){
        int R = Rbase + (nf & 1)*4 + (nf >> 1)*32;
        short8 ak0 = *(const short8*)&Kbuf[R*64 + slot0];
        short8 ak1 = *(const short8*)&Kbuf[R*64 + slot1];
        f32x4 z = {};
        z = __builtin_amdgcn_mfma_f32_16x16x32_bf16(ak0, aq[0], z, 0, 0, 0);
        z = __builtin_amdgcn_mfma_f32_16x16x32_bf16(ak1, aq[1], z, 0, 0, 0);
        float p0 = EXP2(z[0]), p1 = EXP2(z[1]);
        float p2 = EXP2(z[2]), p3 = EXP2(z[3]);
        Wp[nf >> 1][nf & 1][0] = pk2(p0, p1);
        Wp[nf >> 1][nf & 1][1] = pk2(p2, p3);
      }
#pragma unroll
      for (int c=0; c<2; ++c){
        union { uint32_t u4[4]; short8 s; } tt;
        tt.u4[0] = Wp[c][0][0]; tt.u4[1] = Wp[c][0][1];
        tt.u4[2] = Wp[c][1][0]; tt.u4[3] = Wp[c][1][1];
        pa[u][c] = tt.s;
      }
    }
    // PV for both tiles + ones row-sums
#pragma unroll
    for (int u = 0; u < 2; ++u){
      const short* Vbuf = &Vl[(2*p + u) & 3][0];
#pragma unroll
      for (int df=0; df<4; ++df){
        int rowv = (df*16 + lr)*64;
        short8 vb0 = *(const short8*)&Vbuf[rowv + ((lg ^ vx) << 3)];
        short8 vb1 = *(const short8*)&Vbuf[rowv + (((4 + lg) ^ vx) << 3)];
        o[df] = __builtin_amdgcn_mfma_f32_16x16x32_bf16(pa[u][0], vb0, o[df], 0, 0, 0);
        o[df] = __builtin_amdgcn_mfma_f32_16x16x32_bf16(pa[u][1], vb1, o[df], 0, 0, 0);
      }
      o1 = __builtin_amdgcn_mfma_f32_16x16x32_bf16(pa[u][0], ones, o1, 0, 0, 0);
      o1 = __builtin_amdgcn_mfma_f32_16x16x32_bf16(pa[u][1], ones, o1, 0, 0, 0);
    }
    __builtin_amdgcn_s_setprio(0);
    if (p < 15){
      // pair p+1's loads were issued a full pair-compute ago -> vmcnt(0) is a near-no-op;
      // barrier frees pair p's bufs for the pair p+2 issue below.
      asm volatile("s_waitcnt vmcnt(0)" ::: "memory");
      __builtin_amdgcn_sched_barrier(0);
      __builtin_amdgcn_s_barrier();
      if (p < 14){
#pragma unroll
        for (int u = 0; u < 2; ++u){
          int t = 2*p + 4 + u, nb = t & 3;
          gload16(Kb + (size_t)t*4096 + ksrc, (char*)&Kl[nb][0] + koff);
          gload16(Vb + vsrc + t*64,           (char*)&Vl[nb][0] + koff);
        }
      }
    }
  }
  // epilogue: normalize by MFMA-computed row sums, write AO[b][s][h*64+d]
  int b = bh >> 4, hh = bh & 15;
  float rinv[4];
#pragma unroll
  for (int i2=0; i2<4; ++i2) rinv[i2] = 1.0f / o1[i2];
#pragma unroll
  for (int df=0; df<4; ++df)
#pragma unroll
    for (int i2=0; i2<4; ++i2){
      int row = q0 + lg*4 + i2;
      int col = df*16 + lr;
      AO[((size_t)(b*2048 + row))*1024 + hh*64 + col] = f2bf(o[df][i2] * rinv[i2]);
    }
}

extern "C" void kernel_launch(void* const* d_in, const int* in_sizes, int n_in,
                              void* d_out, int out_size, void* d_ws, size_t ws_size,
                              hipStream_t stream){
  const float* q  = (const float*)d_in[0];
  const float* k  = (const float*)d_in[1];
  const float* v  = (const float*)d_in[2];
  const float* Wq = (const float*)d_in[3];
  const float* bq = (const float*)d_in[4];
  const float* Wk = (const float*)d_in[5];
  const float* bk = (const float*)d_in[6];
  const float* Wv = (const float*)d_in[7];
  const float* bv = (const float*)d_in[8];
  const float* Wo = (const float*)d_in[9];
  const float* bo = (const float*)d_in[10];

  const size_t SQ = 4096ull*1024ull, NW = 1024ull*1024ull;
  short* ws  = (short*)d_ws;
  short* qb  = ws;                    // bf16 q      [4096,1024]
  short* kb  = ws + SQ;
  short* vb  = ws + 2*SQ;
  short* Wqb = ws + 3*SQ;             // bf16 weights [1024,1024]
  short* Wkb = Wqb + NW;
  short* Wvb = Wkb + NW;
  short* Wob = Wvb + NW;
  short* Qh  = Wob + NW;              // [B,H,S,D] bf16 (Q pre-scaled by log2e/8)
  short* Kh  = Qh + SQ;
  short* VhT = Kh + SQ;               // [B,H,D,S] bf16 (transposed V projection)
  short* AO  = qb;                    // reuse q buffer for attention output

  const float Csc = 0.18033688011112042f;   // log2(e)/8

  cvt_all<<<4096, 512, 0, stream>>>(q, k, v, Wq, Wk, Wv, Wo, ws);
  gemm_qkv<<<dim3(16, 48), 256, 0, stream>>>(qb, kb, vb, Wqb, Wkb, Wvb, bq, bk, bv, Qh, Kh, VhT, Csc);
  attn_fwd<<<dim3(16, 32), 512, 0, stream>>>(Qh, Kh, VhT, AO);
  gemm_out<<<dim3(16, 16), 512, 0, stream>>>(AO, Wob, bo, (float*)d_out);
}